// Round 16
// baseline (200.831 us; speedup 1.0000x reference)
//
#include <hip/hip_runtime.h>
#include <cstdint>
#include <cstddef>

// ---------------------------------------------------------------------------
// DiT block: LN -> self-attn -> +res -> LN -> cross-attn -> +res -> LN -> MLP
// B=4 N=2048 M=512 E=512 CD=256 H=8 DH=64 MH=1024
// GEMM v4 (r11/r15 best-known): BK=64, XOR-swizzled LDS; TN=64 3-buf depth-2
//   counted-vmcnt(6); TN=128 2-buf depth-1; scalar epilogue.
// Self-attention v10: KV-split x2 flash-decoding (no-max softmax => partials
//   are additive: O=(O0+O1)/(l0+l1)); KVBLK=64, LDS 32KB -> 4 blocks/CU
//   (2x occupancy vs v8). bf16 partial O + fp32 partial l + merge kernel.
// Cross-attention v8 (unchanged): KVBLK=128, 32x32x16, in-register P (T12).
// ---------------------------------------------------------------------------

typedef short short8 __attribute__((ext_vector_type(8)));
typedef short short4v __attribute__((ext_vector_type(4)));
typedef float f32x4 __attribute__((ext_vector_type(4)));
typedef float f32x16 __attribute__((ext_vector_type(16)));

typedef __attribute__((address_space(1))) const void gconst_t;
typedef __attribute__((address_space(3))) void lds_t;

__device__ __forceinline__ void gl_lds16(const void* g, void* l) {
  __builtin_amdgcn_global_load_lds((gconst_t*)g, (lds_t*)l, 16, 0, 0);
}

__device__ __forceinline__ short f2bf(float f) {
  union { float f; unsigned u; } x; x.f = f;
  unsigned r = x.u + 0x7fffu + ((x.u >> 16) & 1u);  // RNE
  return (short)(r >> 16);
}
__device__ __forceinline__ float bf2f(short s) {
  union { unsigned u; float f; } x; x.u = ((unsigned)(unsigned short)s) << 16;
  return x.f;
}

// v_permlane32_swap_b32: a' = {a.lo32lanes, b.lo32lanes}, b' = {a.hi, b.hi}
__device__ __forceinline__ void pl32swap(unsigned& a, unsigned& b) {
  asm("v_permlane32_swap_b32 %0, %1" : "+v"(a), "+v"(b));
}

// ---------------- fused multi-tensor cast fp32 -> bf16 ----------------
struct CastDesc { const float* src; short* dst; int nblk; };
struct CastArgs { CastDesc d[9]; };

__global__ __launch_bounds__(256) void cast_multi(CastArgs a) {
  int bi = blockIdx.x;
#pragma unroll
  for (int i = 0; i < 9; ++i) {
    if (bi < a.d[i].nblk) {
      int idx = (bi * 256 + threadIdx.x) * 8;
      const float* src = a.d[i].src;
      float4 f0 = *(const float4*)(src + idx);
      float4 f1 = *(const float4*)(src + idx + 4);
      short8 o;
      o[0] = f2bf(f0.x); o[1] = f2bf(f0.y); o[2] = f2bf(f0.z); o[3] = f2bf(f0.w);
      o[4] = f2bf(f1.x); o[5] = f2bf(f1.y); o[6] = f2bf(f1.z); o[7] = f2bf(f1.w);
      *(short8*)(a.d[i].dst + idx) = o;
      return;
    }
    bi -= a.d[i].nblk;
  }
}

// ---------------- LayerNorm over 512 cols, 1 wave/row, bf16 out ----------------
template <bool INBF>
__global__ __launch_bounds__(256) void ln_kernel(
    const void* __restrict__ xin, short* __restrict__ out, int nrows) {
  int row = blockIdx.x * 4 + (threadIdx.x >> 6);
  int lane = threadIdx.x & 63;
  if (row >= nrows) return;
  float v[8];
  if constexpr (INBF) {
    const short* xr = (const short*)xin + (size_t)row * 512 + lane * 8;
    short8 a = *(const short8*)xr;
#pragma unroll
    for (int e = 0; e < 8; ++e) v[e] = bf2f(a[e]);
  } else {
    const float* xr = (const float*)xin + (size_t)row * 512 + lane * 8;
    float4 a = *(const float4*)xr;
    float4 b = *(const float4*)(xr + 4);
    v[0] = a.x; v[1] = a.y; v[2] = a.z; v[3] = a.w;
    v[4] = b.x; v[5] = b.y; v[6] = b.z; v[7] = b.w;
  }
  float s = 0.f;
#pragma unroll
  for (int e = 0; e < 8; ++e) s += v[e];
#pragma unroll
  for (int m = 1; m < 64; m <<= 1) s += __shfl_xor(s, m);
  float mean = s * (1.f / 512.f);
  float sq = 0.f;
#pragma unroll
  for (int e = 0; e < 8; ++e) { float d = v[e] - mean; sq += d * d; }
#pragma unroll
  for (int m = 1; m < 64; m <<= 1) sq += __shfl_xor(sq, m);
  float rstd = rsqrtf(sq * (1.f / 512.f) + 1e-6f);
  short8 o;
#pragma unroll
  for (int e = 0; e < 8; ++e) o[e] = f2bf((v[e] - mean) * rstd);
  *(short8*)(out + (size_t)row * 512 + lane * 8) = o;
}

// ---------------- NT GEMM v4: C[R,TN*gx] = A[R,K] * W^T, BK=64, swizzled -----
// TN=64: 4 waves 2x2, wave 64x32, 3 buf, depth-2, vmcnt(6).
// TN=128: 4 waves 2x2, wave 64x64, 2 buf, depth-1, vmcnt(0).
// RESMODE: 0 none, 1 fp32 res, 2 bf16 res.
template <int TN, int RESMODE, bool BIAS, bool RELU, bool OUTBF, bool VT>
__global__ __launch_bounds__(256) void gemm_nt(
    const short* __restrict__ A, const short* __restrict__ W,
    const float* __restrict__ bias, const void* __restrict__ res,
    void* __restrict__ outp, int R, int NC, int K, int gx,
    short* __restrict__ vt, int vcol0, int vn_log2,
    float oscale, int oscale_end) {
  constexpr int NF = TN / 32;             // col frags per wave: 2 or 4
  constexpr int NBUF = (TN == 128) ? 2 : 3;
  __shared__ short As[NBUF][128 * 64];
  __shared__ short Ws[NBUF][TN * 64];
  const int nwg = gridDim.x;
  const int b0 = blockIdx.x;
  const int bid = ((nwg & 7) == 0) ? ((b0 & 7) * (nwg >> 3) + (b0 >> 3)) : b0;
  const int bx = bid % gx, by = bid / gx;
  const int brow = by * 128, bcol = bx * TN;
  const int t = threadIdx.x;
  const int wid = t >> 6, lane = t & 63;
  const int lr = lane & 15, lk = lane >> 4;
  const int wrow = (wid >> 1) * 64, wcol = (wid & 1) * (TN / 2);
  f32x4 acc[4][NF] = {};

  const int srw = lane >> 3;
  const int scol = (((lane & 7) ^ srw) << 3);
  const short* Ag = A + (size_t)(brow + wid * 32 + srw) * K + scol;
  const short* Wg = W + (size_t)(bcol + wid * (TN / 4) + srw) * K + scol;

#define G_STAGE(I, BUF)                                                       \
  {                                                                           \
    const int k0_ = (I) * 64;                                                 \
    gl_lds16(Ag + k0_, &As[BUF][(wid * 32) * 64]);                            \
    gl_lds16(Ag + (size_t)8 * K + k0_, &As[BUF][(wid * 32 + 8) * 64]);        \
    gl_lds16(Ag + (size_t)16 * K + k0_, &As[BUF][(wid * 32 + 16) * 64]);      \
    gl_lds16(Ag + (size_t)24 * K + k0_, &As[BUF][(wid * 32 + 24) * 64]);      \
    if constexpr (TN == 128) {                                                \
      gl_lds16(Wg + k0_, &Ws[BUF][(wid * 32) * 64]);                          \
      gl_lds16(Wg + (size_t)8 * K + k0_, &Ws[BUF][(wid * 32 + 8) * 64]);      \
      gl_lds16(Wg + (size_t)16 * K + k0_, &Ws[BUF][(wid * 32 + 16) * 64]);    \
      gl_lds16(Wg + (size_t)24 * K + k0_, &Ws[BUF][(wid * 32 + 24) * 64]);    \
    } else {                                                                  \
      gl_lds16(Wg + k0_, &Ws[BUF][(wid * 16) * 64]);                          \
      gl_lds16(Wg + (size_t)8 * K + k0_, &Ws[BUF][(wid * 16 + 8) * 64]);      \
    }                                                                         \
  }

  const int ns = K / 64;

#define G_COMPUTE(CUR)                                                        \
  {                                                                           \
    _Pragma("unroll")                                                         \
    for (int kc = 0; kc < 2; ++kc) {                                          \
      short8 af[4], bf[NF];                                                   \
      _Pragma("unroll")                                                       \
      for (int mi = 0; mi < 4; ++mi) {                                        \
        const int row = wrow + mi * 16 + lr;                                  \
        af[mi] = *(const short8*)&As[CUR][row * 64 +                          \
                                          (((kc * 4 + lk) ^ (row & 7)) << 3)];\
      }                                                                       \
      _Pragma("unroll")                                                       \
      for (int ni = 0; ni < NF; ++ni) {                                       \
        const int row = wcol + ni * 16 + lr;                                  \
        bf[ni] = *(const short8*)&Ws[CUR][row * 64 +                          \
                                          (((kc * 4 + lk) ^ (row & 7)) << 3)];\
      }                                                                       \
      _Pragma("unroll")                                                       \
      for (int mi = 0; mi < 4; ++mi)                                          \
        _Pragma("unroll")                                                     \
        for (int ni = 0; ni < NF; ++ni)                                       \
          acc[mi][ni] = __builtin_amdgcn_mfma_f32_16x16x32_bf16(              \
              af[mi], bf[ni], acc[mi][ni], 0, 0, 0);                          \
    }                                                                         \
  }

  if constexpr (TN == 128) {
    // 2-buffer depth-1 pipeline
    G_STAGE(0, 0);
    asm volatile("s_waitcnt vmcnt(0)" ::: "memory");
    __builtin_amdgcn_s_barrier();
    for (int i = 0; i < ns; ++i) {
      const int cur = i & 1;
      if (i + 1 < ns) G_STAGE(i + 1, cur ^ 1);
      G_COMPUTE(cur);
      if (i + 1 < ns) {
        asm volatile("s_waitcnt vmcnt(0) lgkmcnt(0)" ::: "memory");
        __builtin_amdgcn_s_barrier();
      }
    }
  } else {
    // 3-buffer depth-2 pipeline (counted vmcnt, never 0 mid-loop)
    G_STAGE(0, 0);
    G_STAGE(1, 1);
    asm volatile("s_waitcnt vmcnt(6)" ::: "memory");
    __builtin_amdgcn_s_barrier();
    for (int i = 0; i < ns; ++i) {
      const int cur = i % 3;
      if (i + 2 < ns) G_STAGE(i + 2, (i + 2) % 3);
      G_COMPUTE(cur);
      if (i + 1 < ns) {
        if (i + 2 < ns)
          asm volatile("s_waitcnt vmcnt(6) lgkmcnt(0)" ::: "memory");
        else
          asm volatile("s_waitcnt vmcnt(0) lgkmcnt(0)" ::: "memory");
        __builtin_amdgcn_s_barrier();
      }
    }
  }
#undef G_STAGE
#undef G_COMPUTE

  if (VT && bcol >= vcol0) {
    const int vn_mask = (1 << vn_log2) - 1;
#pragma unroll
    for (int mi = 0; mi < 4; ++mi) {
#pragma unroll
      for (int ni = 0; ni < NF; ++ni) {
        int col = bcol + wcol + ni * 16 + lr;
        int vc = col - vcol0;
        int r0 = brow + wrow + mi * 16 + lk * 4;
        int bb = r0 >> vn_log2;
        int n = r0 & vn_mask;
        float bv = BIAS ? bias[col] : 0.f;
        short4v o;
#pragma unroll
        for (int j = 0; j < 4; ++j) o[j] = f2bf(acc[mi][ni][j] + bv);
        *(short4v*)(vt + (((size_t)(bb * 512 + vc)) << vn_log2) + n) = o;
      }
    }
    return;
  }

#pragma unroll
  for (int mi = 0; mi < 4; ++mi) {
#pragma unroll
    for (int ni = 0; ni < NF; ++ni) {
      int col = bcol + wcol + ni * 16 + lr;
      int row0 = brow + wrow + mi * 16 + lk * 4;
      float bv = BIAS ? bias[col] : 0.f;
#pragma unroll
      for (int j = 0; j < 4; ++j) {
        float v = acc[mi][ni][j] + bv;
        if (RELU) v = fmaxf(v, 0.f);
        if (col < oscale_end) v *= oscale;
        size_t oi = (size_t)(row0 + j) * NC + col;
        if (RESMODE == 1) v += ((const float*)res)[oi];
        if (RESMODE == 2) v += bf2f(((const short*)res)[oi]);
        if (OUTBF) ((short*)outp)[oi] = f2bf(v);
        else       ((float*)outp)[oi] = v;
      }
    }
  }
}

// ---------------- Flash attention v8 (cross-attn; KVBLK=128, unchanged) -----
__global__ __launch_bounds__(256) void flash_attn8(
    const short* __restrict__ q, const short* __restrict__ k,
    const short* __restrict__ vt, short* __restrict__ out,
    int qstride, int kstride, int Nq, int Nkv, int vn_log2, int H_) {
  __shared__ short Ks[2 * 128 * 64];   // 32 KB
  __shared__ short Vs[2 * 64 * 128];   // 32 KB
  const int t = threadIdx.x;
  const int wid = t >> 6, lane = t & 63;
  const int l31 = lane & 31, lh = lane >> 5;
  const int nb = gridDim.x;
  const int b0 = blockIdx.x;
  const int bid = ((nb & 7) == 0) ? ((b0 & 7) * (nb >> 3) + (b0 >> 3)) : b0;
  const int gx = Nq >> 7;
  const int bh = bid / gx, qblk = bid - bh * gx;
  const int b = bh / H_, h = bh - b * H_;
  const int q0 = qblk * 128 + wid * 32;

  short8 qf[4];
  {
    const short* qp = q + ((size_t)b * Nq + q0 + l31) * qstride + h * 64 + lh * 8;
#pragma unroll
    for (int kc = 0; kc < 4; ++kc) qf[kc] = *(const short8*)(qp + kc * 16);
  }

  f32x16 o0 = {}, o1 = {};
  f32x16 lacc = {};

  const int krw = lane >> 3;
  const short* kG = k + ((size_t)b * Nkv + wid * 32 + krw) * kstride + h * 64 +
                    (((lane & 7) ^ krw) << 3);
  const short* vGp[4];
#pragma unroll
  for (int j = 0; j < 4; ++j)
    vGp[j] = vt + (((size_t)bh * 64 + wid * 16 + j * 4 + (lane >> 4)) << vn_log2) +
             (((lane & 15) ^ (j * 4 + (lane >> 4))) << 3);
  short* kD = &Ks[wid * 2048];
  short* vD = &Vs[wid * 2048];

#define STAGE_KV(KT, BUF)                                                     \
  {                                                                           \
    const short* kp_ = kG + (size_t)(KT) * kstride;                           \
    short* kd_ = kD + (BUF) * 8192;                                           \
    gl_lds16(kp_, kd_);                                                       \
    gl_lds16(kp_ + (size_t)8 * kstride, kd_ + 512);                           \
    gl_lds16(kp_ + (size_t)16 * kstride, kd_ + 1024);                         \
    gl_lds16(kp_ + (size_t)24 * kstride, kd_ + 1536);                         \
    short* vd_ = vD + (BUF) * 8192;                                           \
    gl_lds16(vGp[0] + (KT), vd_);                                             \
    gl_lds16(vGp[1] + (KT), vd_ + 512);                                       \
    gl_lds16(vGp[2] + (KT), vd_ + 1024);                                      \
    gl_lds16(vGp[3] + (KT), vd_ + 1536);                                      \
  }

  STAGE_KV(0, 0);
  __syncthreads();
  int cur = 0;

  for (int kt = 0; kt < Nkv; kt += 128) {
    if (kt + 128 < Nkv) STAGE_KV(kt + 128, cur ^ 1);

    const short* kbase = &Ks[cur * 8192];
    const short* vbase = &Vs[cur * 8192];

#pragma unroll
    for (int kk = 0; kk < 4; ++kk) {
      f32x16 s = {};
      {
        const int r = kk * 32 + l31;
        const short* krow = kbase + r * 64;
        const int rx = r & 7;
#pragma unroll
        for (int kc = 0; kc < 4; ++kc) {
          short8 kf = *(const short8*)(krow + (((kc * 2 + lh) ^ rx) << 3));
          s = __builtin_amdgcn_mfma_f32_32x32x16_bf16(kf, qf[kc], s, 0, 0, 0);
        }
      }
#pragma unroll
      for (int rr = 0; rr < 16; ++rr)
        s[rr] = __builtin_amdgcn_exp2f(s[rr]);
      lacc += s;
      unsigned w[8];
#pragma unroll
      for (int g = 0; g < 8; ++g)
        asm("v_cvt_pk_bf16_f32 %0, %1, %2" : "=v"(w[g]) : "v"(s[2 * g]), "v"(s[2 * g + 1]));
      pl32swap(w[0], w[2]); pl32swap(w[1], w[3]);
      pl32swap(w[4], w[6]); pl32swap(w[5], w[7]);
      union { unsigned u[4]; short8 s8; } pf0, pf1;
      pf0.u[0] = w[0]; pf0.u[1] = w[1]; pf0.u[2] = w[2]; pf0.u[3] = w[3];
      pf1.u[0] = w[4]; pf1.u[1] = w[5]; pf1.u[2] = w[6]; pf1.u[3] = w[7];
#pragma unroll
      for (int ch = 0; ch < 2; ++ch) {
        short8 pf = ch ? pf1.s8 : pf0.s8;
        const int c16 = kk * 4 + ch * 2 + lh;
        {
          const int d = l31;
          short8 vf = *(const short8*)(vbase + d * 128 + ((c16 ^ (d & 15)) << 3));
          o0 = __builtin_amdgcn_mfma_f32_32x32x16_bf16(vf, pf, o0, 0, 0, 0);
        }
        {
          const int d = 32 + l31;
          short8 vf = *(const short8*)(vbase + d * 128 + ((c16 ^ (d & 15)) << 3));
          o1 = __builtin_amdgcn_mfma_f32_32x32x16_bf16(vf, pf, o1, 0, 0, 0);
        }
      }
    }

    __syncthreads();
    cur ^= 1;
  }
#undef STAGE_KV

  float ls = (((lacc[0] + lacc[1]) + (lacc[2] + lacc[3])) +
              ((lacc[4] + lacc[5]) + (lacc[6] + lacc[7]))) +
             (((lacc[8] + lacc[9]) + (lacc[10] + lacc[11])) +
              ((lacc[12] + lacc[13]) + (lacc[14] + lacc[15])));
  ls += __shfl_xor(ls, 32);
  float inv = 1.f / ls;

  short* orow = out + ((size_t)b * Nq + q0 + l31) * 512 + h * 64 + 4 * lh;
#pragma unroll
  for (int g = 0; g < 4; ++g) {
    short4v w0, w1;
#pragma unroll
    for (int j = 0; j < 4; ++j) {
      w0[j] = f2bf(o0[4 * g + j] * inv);
      w1[j] = f2bf(o1[4 * g + j] * inv);
    }
    *(short4v*)(orow + 8 * g) = w0;
    *(short4v*)(orow + 32 + 8 * g) = w1;
  }
}

// ---------------- Flash attention v10: KV-split x2, KVBLK=64 ----------------
// grid: (Nq/128)*B*H*2 blocks; bid -> {split, bh, qblk}. Each block processes
// kv range [split*Nkv/2, +Nkv/2) in 64-kv tiles (LDS 32KB -> 4 blocks/CU).
// No-max softmax => partials additive: writes UNNORMALIZED O (bf16) + l (f32).
__global__ __launch_bounds__(256) void flash_attn10(
    const short* __restrict__ q, const short* __restrict__ k,
    const short* __restrict__ vt, short* __restrict__ opart,
    float* __restrict__ lpart,
    int qstride, int kstride, int Nq, int Nkv, int vn_log2, int H_) {
  __shared__ short Ks[2 * 64 * 64];   // 16 KB
  __shared__ short Vs[2 * 64 * 64];   // 16 KB
  const int t = threadIdx.x;
  const int wid = t >> 6, lane = t & 63;
  const int l31 = lane & 31, lh = lane >> 5;
  const int nb = gridDim.x;
  const int b0 = blockIdx.x;
  const int bid = ((nb & 7) == 0) ? ((b0 & 7) * (nb >> 3) + (b0 >> 3)) : b0;
  const int split = bid & 1;
  const int rest = bid >> 1;
  const int gx = Nq >> 7;
  const int bh = rest / gx, qblk = rest - bh * gx;
  const int b = bh / H_, h = bh - b * H_;
  const int q0 = qblk * 128 + wid * 32;
  const int kvlen = Nkv >> 1;
  const int kt0 = split * kvlen;

  short8 qf[4];
  {
    const short* qp = q + ((size_t)b * Nq + q0 + l31) * qstride + h * 64 + lh * 8;
#pragma unroll
    for (int kc = 0; kc < 4; ++kc) qf[kc] = *(const short8*)(qp + kc * 16);
  }

  f32x16 o0 = {}, o1 = {};
  f32x16 lacc = {};

  // staging: per glds a wave covers 8 rows x 128B; row-in-call = lane>>3,
  // 16B col-block = lane&7 (8 blocks), source block XORed with row&7.
  const int srw8 = lane >> 3;
  const int scb = ((lane & 7) ^ srw8) << 3;
  const short* kG = k + ((size_t)b * Nkv + wid * 16 + srw8) * kstride + h * 64 + scb;
  const short* vG = vt + (((size_t)bh * 64 + wid * 16 + srw8) << vn_log2) + scb;
  short* kD = &Ks[wid * 1024];
  short* vD = &Vs[wid * 1024];

#define STAGE_KV64(KT, BUF)                                                   \
  {                                                                           \
    const short* kp_ = kG + (size_t)(KT) * kstride;                           \
    gl_lds16(kp_, kD + (BUF) * 4096);                                         \
    gl_lds16(kp_ + (size_t)8 * kstride, kD + (BUF) * 4096 + 512);             \
    const short* vp_ = vG + (KT);                                             \
    gl_lds16(vp_, vD + (BUF) * 4096);                                         \
    gl_lds16(vp_ + ((size_t)8 << vn_log2), vD + (BUF) * 4096 + 512);          \
  }

  STAGE_KV64(kt0, 0);
  __syncthreads();
  int cur = 0;

  for (int kt = kt0; kt < kt0 + kvlen; kt += 64) {
    if (kt + 64 < kt0 + kvlen) STAGE_KV64(kt + 64, cur ^ 1);

    const short* kbase = &Ks[cur * 4096];
    const short* vbase = &Vs[cur * 4096];

#pragma unroll
    for (int kk = 0; kk < 2; ++kk) {
      f32x16 s = {};
      {
        const int r = kk * 32 + l31;
        const short* krow = kbase + r * 64;
        const int rx = r & 7;
#pragma unroll
        for (int kc = 0; kc < 4; ++kc) {
          short8 kf = *(const short8*)(krow + (((kc * 2 + lh) ^ rx) << 3));
          s = __builtin_amdgcn_mfma_f32_32x32x16_bf16(kf, qf[kc], s, 0, 0, 0);
        }
      }
#pragma unroll
      for (int rr = 0; rr < 16; ++rr)
        s[rr] = __builtin_amdgcn_exp2f(s[rr]);
      lacc += s;
      unsigned w[8];
#pragma unroll
      for (int g = 0; g < 8; ++g)
        asm("v_cvt_pk_bf16_f32 %0, %1, %2" : "=v"(w[g]) : "v"(s[2 * g]), "v"(s[2 * g + 1]));
      pl32swap(w[0], w[2]); pl32swap(w[1], w[3]);
      pl32swap(w[4], w[6]); pl32swap(w[5], w[7]);
      union { unsigned u[4]; short8 s8; } pf0, pf1;
      pf0.u[0] = w[0]; pf0.u[1] = w[1]; pf0.u[2] = w[2]; pf0.u[3] = w[3];
      pf1.u[0] = w[4]; pf1.u[1] = w[5]; pf1.u[2] = w[6]; pf1.u[3] = w[7];
#pragma unroll
      for (int ch = 0; ch < 2; ++ch) {
        short8 pf = ch ? pf1.s8 : pf0.s8;
        const int c8 = kk * 4 + ch * 2 + lh;   // 16B block within 64 kv
        {
          const int d = l31;
          short8 vf = *(const short8*)(vbase + d * 64 + ((c8 ^ (d & 7)) << 3));
          o0 = __builtin_amdgcn_mfma_f32_32x32x16_bf16(vf, pf, o0, 0, 0, 0);
        }
        {
          const int d = 32 + l31;
          short8 vf = *(const short8*)(vbase + d * 64 + ((c8 ^ (d & 7)) << 3));
          o1 = __builtin_amdgcn_mfma_f32_32x32x16_bf16(vf, pf, o1, 0, 0, 0);
        }
      }
    }

    __syncthreads();
    cur ^= 1;
  }
#undef STAGE_KV64

  float ls = (((lacc[0] + lacc[1]) + (lacc[2] + lacc[3])) +
              ((lacc[4] + lacc[5]) + (lacc[6] + lacc[7]))) +
             (((lacc[8] + lacc[9]) + (lacc[10] + lacc[11])) +
              ((lacc[12] + lacc[13]) + (lacc[14] + lacc[15])));
  ls += __shfl_xor(ls, 32);

  // unnormalized partial write: opart[(split*BH + bh)][q][64] bf16
  const size_t prow = ((size_t)(split * 32 + bh) * Nq + q0 + l31);
  short* orow = opart + prow * 64 + 4 * lh;
#pragma unroll
  for (int g = 0; g < 4; ++g) {
    short4v w0, w1;
#pragma unroll
    for (int j = 0; j < 4; ++j) {
      w0[j] = f2bf(o0[4 * g + j]);
      w1[j] = f2bf(o1[4 * g + j]);
    }
    *(short4v*)(orow + 8 * g) = w0;
    *(short4v*)(orow + 32 + 8 * g) = w1;
  }
  if (lh == 0) lpart[prow] = ls;
}

// ---------------- merge: out = (O0 + O1) / (l0 + l1), bf16 -------------------
// block = 256 thr = 32 rows x 8 col-chunks of 8. BHN = B*H*Nq rows.
__global__ __launch_bounds__(256) void merge_attn(
    const short* __restrict__ oP, const float* __restrict__ lP,
    short* __restrict__ out, int Nq, int H_, int BHN) {
  const int t = threadIdx.x;
  const int R = blockIdx.x * 32 + (t >> 3);
  const int d0 = (t & 7) * 8;
  const int bh = R / Nq, qq = R - bh * Nq;
  const int b = bh / H_, h = bh - b * H_;
  short8 a = *(const short8*)(oP + (size_t)R * 64 + d0);
  short8 c = *(const short8*)(oP + ((size_t)BHN + R) * 64 + d0);
  float inv = 1.f / (lP[R] + lP[BHN + R]);
  short8 o;
#pragma unroll
  for (int j = 0; j < 8; ++j) o[j] = f2bf((bf2f(a[j]) + bf2f(c[j])) * inv);
  *(short8*)(out + ((size_t)(b * Nq + qq)) * 512 + h * 64 + d0) = o;
}

// ---------------------------------------------------------------------------
extern "C" void kernel_launch(void* const* d_in, const int* in_sizes, int n_in,
                              void* d_out, int out_size, void* d_ws, size_t ws_size,
                              hipStream_t stream) {
  (void)in_sizes; (void)n_in; (void)out_size; (void)ws_size;
  const float* cond  = (const float*)d_in[0];
  const float* x_in  = (const float*)d_in[1];
  const float* Wqkv  = (const float*)d_in[2];
  const float* b_qkv = (const float*)d_in[3];
  const float* Wo    = (const float*)d_in[4];
  const float* bo    = (const float*)d_in[5];
  const float* Wcq   = (const float*)d_in[6];
  const float* Wck   = (const float*)d_in[7];
  const float* Wcv   = (const float*)d_in[8];
  const float* Wco   = (const float*)d_in[9];
  const float* bco   = (const float*)d_in[10];
  const float* W1    = (const float*)d_in[11];
  const float* b1    = (const float*)d_in[12];
  const float* W2    = (const float*)d_in[13];
  const float* b2    = (const float*)d_in[14];
  float* out = (float*)d_out;

  const int Bv = 4, Nv = 2048, Mv = 512, Ev = 512, Hv = 8, MHv = 1024, CDv = 256;
  const int RN = Bv * Nv;   // 8192
  const int RM = Bv * Mv;   // 2048
  const int BHN = Bv * Hv * Nv;   // 65536 attention rows
  const float KSC = 0.125f * 1.44269504f;  // softmax scale * log2(e) -> folded into Q

  char* ws = (char*)d_ws;
  size_t off = 0;
  auto alloc = [&](size_t bytes) { void* p = ws + off; off += bytes; return p; };

  short* wqkv_b = (short*)alloc((size_t)3 * Ev * Ev * 2);
  short* wo_b   = (short*)alloc((size_t)Ev * Ev * 2);
  short* wcq_b  = (short*)alloc((size_t)Ev * Ev * 2);
  short* wck_b  = (short*)alloc((size_t)Ev * CDv * 2);   // adjacent to wcv_b!
  short* wcv_b  = (short*)alloc((size_t)Ev * CDv * 2);
  short* wco_b  = (short*)alloc((size_t)Ev * Ev * 2);
  short* w1_b   = (short*)alloc((size_t)MHv * Ev * 2);
  short* w2_b   = (short*)alloc((size_t)Ev * MHv * 2);
  short* cond_b = (short*)alloc((size_t)RM * CDv * 2);
  short* xnb    = (short*)alloc((size_t)RN * Ev * 2);          // xn/xn2/xn3
  short* sa_b   = (short*)alloc((size_t)RN * Ev * 2);
  short* x1     = (short*)alloc((size_t)RN * Ev * 2);          // bf16 residual
  short* x2     = (short*)alloc((size_t)RN * Ev * 2);          // bf16 residual
  short* oP     = (short*)alloc((size_t)2 * BHN * 64 * 2);     // 16.8MB partial O
  float* lP     = (float*)alloc((size_t)2 * BHN * 4);          // 0.5MB partial l
  char*  qreg   = (char*)alloc((size_t)RN * 3 * Ev * 2);       // 25.2MB region
  short* qkv_b  = (short*)qreg;
  // aliases (disjoint lifetimes):
  short* cq   = (short*)(qreg + 0);                                       // 8MB
  short* ck   = (short*)(qreg + (size_t)RN * Ev * 2);                     // 4MB (stride 1024)
  short* vt_c = (short*)(qreg + (size_t)RN * Ev * 2 + (size_t)4 * 1024 * 1024);
  short* ca   = (short*)(qreg + (size_t)RN * Ev * 2 + (size_t)6 * 1024 * 1024);
  short* hb   = (short*)(qreg + 0);          // MLP hidden, after cross-attn
  short* vt_s = (short*)x2;                  // self V^T (8.4MB), dead before x2 write

  // fused weight/cond casts
  CastArgs ca_args;
  const float* srcs[9] = {Wqkv, Wo, Wcq, Wck, Wcv, Wco, W1, W2, cond};
  short* dsts[9] = {wqkv_b, wo_b, wcq_b, wck_b, wcv_b, wco_b, w1_b, w2_b, cond_b};
  int ns_[9] = {3*Ev*Ev, Ev*Ev, Ev*Ev, Ev*CDv, Ev*CDv, Ev*Ev, MHv*Ev, Ev*MHv, RM*CDv};
  int tot_blk = 0;
  for (int i = 0; i < 9; ++i) {
    ca_args.d[i].src = srcs[i]; ca_args.d[i].dst = dsts[i];
    ca_args.d[i].nblk = ns_[i] / 2048; tot_blk += ca_args.d[i].nblk;
  }
  cast_multi<<<tot_blk, 256, 0, stream>>>(ca_args);

  dim3 blk(256);

  // 1) LN(x_in fp32) -> xnb
  ln_kernel<false><<<RN / 4, blk, 0, stream>>>(x_in, xnb, RN);
  // 2) qkv (TN=128): q (cols<512, pre-scaled KSC), k -> qkv_b; v -> vt_s^T
  gemm_nt<128, 0, true, false, true, true><<<(3 * Ev / 128) * (RN / 128), blk, 0, stream>>>(
      xnb, wqkv_b, b_qkv, nullptr, qkv_b, RN, 3 * Ev, Ev, 3 * Ev / 128,
      vt_s, 2 * Ev, 11, KSC, Ev);
  // 3) self-attn: KV-split x2 partials + merge
  flash_attn10<<<(Nv / 128) * Bv * Hv * 2, blk, 0, stream>>>(
      qkv_b, qkv_b + Ev, vt_s, oP, lP, 3 * Ev, 3 * Ev, Nv, Nv, 11, Hv);
  merge_attn<<<BHN / 32, blk, 0, stream>>>(oP, lP, sa_b, Nv, Hv, BHN);
  // 4) x1 = sa @ Wo^T + bo + x_in  (bf16 out, fp32 res)
  gemm_nt<64, 1, true, false, true, false><<<(Ev / 64) * (RN / 128), blk, 0, stream>>>(
      sa_b, wo_b, bo, x_in, x1, RN, Ev, Ev, Ev / 64, nullptr, 0, 0, 1.f, 0);
  // 5) LN(x1 bf16) -> xnb
  ln_kernel<true><<<RN / 4, blk, 0, stream>>>(x1, xnb, RN);
  // 6) cq = (xnb @ Wcq^T) * KSC
  gemm_nt<64, 0, false, false, true, false><<<(Ev / 64) * (RN / 128), blk, 0, stream>>>(
      xnb, wcq_b, nullptr, nullptr, cq, RN, Ev, Ev, Ev / 64, nullptr, 0, 0, KSC, Ev);
  // 7) [ck | cv] = cond @ [Wck;Wcv]^T one GEMM; cv half -> vt_c transposed
  gemm_nt<64, 0, false, false, true, true><<<(2 * Ev / 64) * (RM / 128), blk, 0, stream>>>(
      cond_b, wck_b, nullptr, nullptr, ck, RM, 2 * Ev, CDv, 2 * Ev / 64,
      vt_c, Ev, 9, 1.f, 0);
  // 8) cross-attn (v8 unchanged; k rows stride 1024)
  flash_attn8<<<(Nv / 128) * Bv * Hv, blk, 0, stream>>>(
      cq, ck, vt_c, ca, Ev, 2 * Ev, Nv, Mv, 9, Hv);
  // 9) x2 = ca @ Wco^T + bco + x1 (bf16 out, bf16 res)
  gemm_nt<64, 2, true, false, true, false><<<(Ev / 64) * (RN / 128), blk, 0, stream>>>(
      ca, wco_b, bco, x1, x2, RN, Ev, Ev, Ev / 64, nullptr, 0, 0, 1.f, 0);
  // 10) LN(x2 bf16) -> xnb
  ln_kernel<true><<<RN / 4, blk, 0, stream>>>(x2, xnb, RN);
  // 11) h = relu(xnb @ W1^T + b1)  (TN=128)
  gemm_nt<128, 0, true, true, true, false><<<(MHv / 128) * (RN / 128), blk, 0, stream>>>(
      xnb, w1_b, b1, nullptr, hb, RN, MHv, Ev, MHv / 128, nullptr, 0, 0, 1.f, 0);
  // 12) out = relu(h @ W2^T + b2) + x2 (fp32 out, bf16 res)
  gemm_nt<64, 2, true, true, false, false><<<(Ev / 64) * (RN / 128), blk, 0, stream>>>(
      hb, w2_b, b2, x2, out, RN, Ev, MHv, Ev / 64, nullptr, 0, 0, 1.f, 0);
}

// Round 17
// 188.120 us; speedup vs baseline: 1.0676x; 1.0676x over previous
//
#include <hip/hip_runtime.h>
#include <cstdint>
#include <cstddef>

// ---------------------------------------------------------------------------
// DiT block: LN -> self-attn -> +res -> LN -> cross-attn -> +res -> LN -> MLP
// B=4 N=2048 M=512 E=512 CD=256 H=8 DH=64 MH=1024
// FINAL (r15 configuration — session best, 189 us):
// GEMM v4: BK=64, XOR-swizzled LDS (16B-block ^ row&7 folded into glds SOURCE);
//   TN=64 3-buf depth-2 counted-vmcnt(6); TN=128 2-buf depth-1; scalar epilogue.
// Attention v8: 32x32x16 swapped QK^T, no-max exp2 softmax (scale folded into
//   Q producer GEMMs), in-register P via cvt_pk + permlane32_swap (T12),
//   K/V LDS-staged via global_load_lds + source-side XOR swizzle, dbuf.
// ---------------------------------------------------------------------------

typedef short short8 __attribute__((ext_vector_type(8)));
typedef short short4v __attribute__((ext_vector_type(4)));
typedef float f32x4 __attribute__((ext_vector_type(4)));
typedef float f32x16 __attribute__((ext_vector_type(16)));

typedef __attribute__((address_space(1))) const void gconst_t;
typedef __attribute__((address_space(3))) void lds_t;

__device__ __forceinline__ void gl_lds16(const void* g, void* l) {
  __builtin_amdgcn_global_load_lds((gconst_t*)g, (lds_t*)l, 16, 0, 0);
}

__device__ __forceinline__ short f2bf(float f) {
  union { float f; unsigned u; } x; x.f = f;
  unsigned r = x.u + 0x7fffu + ((x.u >> 16) & 1u);  // RNE
  return (short)(r >> 16);
}
__device__ __forceinline__ float bf2f(short s) {
  union { unsigned u; float f; } x; x.u = ((unsigned)(unsigned short)s) << 16;
  return x.f;
}

// v_permlane32_swap_b32: a' = {a.lo32lanes, b.lo32lanes}, b' = {a.hi, b.hi}
__device__ __forceinline__ void pl32swap(unsigned& a, unsigned& b) {
  asm("v_permlane32_swap_b32 %0, %1" : "+v"(a), "+v"(b));
}

// ---------------- fused multi-tensor cast fp32 -> bf16 ----------------
struct CastDesc { const float* src; short* dst; int nblk; };
struct CastArgs { CastDesc d[9]; };

__global__ __launch_bounds__(256) void cast_multi(CastArgs a) {
  int bi = blockIdx.x;
#pragma unroll
  for (int i = 0; i < 9; ++i) {
    if (bi < a.d[i].nblk) {
      int idx = (bi * 256 + threadIdx.x) * 8;
      const float* src = a.d[i].src;
      float4 f0 = *(const float4*)(src + idx);
      float4 f1 = *(const float4*)(src + idx + 4);
      short8 o;
      o[0] = f2bf(f0.x); o[1] = f2bf(f0.y); o[2] = f2bf(f0.z); o[3] = f2bf(f0.w);
      o[4] = f2bf(f1.x); o[5] = f2bf(f1.y); o[6] = f2bf(f1.z); o[7] = f2bf(f1.w);
      *(short8*)(a.d[i].dst + idx) = o;
      return;
    }
    bi -= a.d[i].nblk;
  }
}

// ---------------- LayerNorm over 512 cols, 1 wave/row, bf16 out ----------------
template <bool INBF>
__global__ __launch_bounds__(256) void ln_kernel(
    const void* __restrict__ xin, short* __restrict__ out, int nrows) {
  int row = blockIdx.x * 4 + (threadIdx.x >> 6);
  int lane = threadIdx.x & 63;
  if (row >= nrows) return;
  float v[8];
  if constexpr (INBF) {
    const short* xr = (const short*)xin + (size_t)row * 512 + lane * 8;
    short8 a = *(const short8*)xr;
#pragma unroll
    for (int e = 0; e < 8; ++e) v[e] = bf2f(a[e]);
  } else {
    const float* xr = (const float*)xin + (size_t)row * 512 + lane * 8;
    float4 a = *(const float4*)xr;
    float4 b = *(const float4*)(xr + 4);
    v[0] = a.x; v[1] = a.y; v[2] = a.z; v[3] = a.w;
    v[4] = b.x; v[5] = b.y; v[6] = b.z; v[7] = b.w;
  }
  float s = 0.f;
#pragma unroll
  for (int e = 0; e < 8; ++e) s += v[e];
#pragma unroll
  for (int m = 1; m < 64; m <<= 1) s += __shfl_xor(s, m);
  float mean = s * (1.f / 512.f);
  float sq = 0.f;
#pragma unroll
  for (int e = 0; e < 8; ++e) { float d = v[e] - mean; sq += d * d; }
#pragma unroll
  for (int m = 1; m < 64; m <<= 1) sq += __shfl_xor(sq, m);
  float rstd = rsqrtf(sq * (1.f / 512.f) + 1e-6f);
  short8 o;
#pragma unroll
  for (int e = 0; e < 8; ++e) o[e] = f2bf((v[e] - mean) * rstd);
  *(short8*)(out + (size_t)row * 512 + lane * 8) = o;
}

// ---------------- NT GEMM v4: C[R,TN*gx] = A[R,K] * W^T, BK=64, swizzled -----
// TN=64: 4 waves 2x2, wave 64x32, 3 buf, depth-2, vmcnt(6).
// TN=128: 4 waves 2x2, wave 64x64, 2 buf, depth-1, vmcnt(0).
// RESMODE: 0 none, 1 fp32 res, 2 bf16 res.
template <int TN, int RESMODE, bool BIAS, bool RELU, bool OUTBF, bool VT>
__global__ __launch_bounds__(256) void gemm_nt(
    const short* __restrict__ A, const short* __restrict__ W,
    const float* __restrict__ bias, const void* __restrict__ res,
    void* __restrict__ outp, int R, int NC, int K, int gx,
    short* __restrict__ vt, int vcol0, int vn_log2,
    float oscale, int oscale_end) {
  constexpr int NF = TN / 32;             // col frags per wave: 2 or 4
  constexpr int NBUF = (TN == 128) ? 2 : 3;
  __shared__ short As[NBUF][128 * 64];
  __shared__ short Ws[NBUF][TN * 64];
  const int nwg = gridDim.x;
  const int b0 = blockIdx.x;
  const int bid = ((nwg & 7) == 0) ? ((b0 & 7) * (nwg >> 3) + (b0 >> 3)) : b0;
  const int bx = bid % gx, by = bid / gx;
  const int brow = by * 128, bcol = bx * TN;
  const int t = threadIdx.x;
  const int wid = t >> 6, lane = t & 63;
  const int lr = lane & 15, lk = lane >> 4;
  const int wrow = (wid >> 1) * 64, wcol = (wid & 1) * (TN / 2);
  f32x4 acc[4][NF] = {};

  // staging: per glds call a wave covers 8 rows x 128B; row-in-call = lane>>3,
  // 16B col-block = lane&7, source col-block XORed with row&7 (= lane>>3).
  const int srw = lane >> 3;
  const int scol = (((lane & 7) ^ srw) << 3);
  const short* Ag = A + (size_t)(brow + wid * 32 + srw) * K + scol;
  const short* Wg = W + (size_t)(bcol + wid * (TN / 4) + srw) * K + scol;

#define G_STAGE(I, BUF)                                                       \
  {                                                                           \
    const int k0_ = (I) * 64;                                                 \
    gl_lds16(Ag + k0_, &As[BUF][(wid * 32) * 64]);                            \
    gl_lds16(Ag + (size_t)8 * K + k0_, &As[BUF][(wid * 32 + 8) * 64]);        \
    gl_lds16(Ag + (size_t)16 * K + k0_, &As[BUF][(wid * 32 + 16) * 64]);      \
    gl_lds16(Ag + (size_t)24 * K + k0_, &As[BUF][(wid * 32 + 24) * 64]);      \
    if constexpr (TN == 128) {                                                \
      gl_lds16(Wg + k0_, &Ws[BUF][(wid * 32) * 64]);                          \
      gl_lds16(Wg + (size_t)8 * K + k0_, &Ws[BUF][(wid * 32 + 8) * 64]);      \
      gl_lds16(Wg + (size_t)16 * K + k0_, &Ws[BUF][(wid * 32 + 16) * 64]);    \
      gl_lds16(Wg + (size_t)24 * K + k0_, &Ws[BUF][(wid * 32 + 24) * 64]);    \
    } else {                                                                  \
      gl_lds16(Wg + k0_, &Ws[BUF][(wid * 16) * 64]);                          \
      gl_lds16(Wg + (size_t)8 * K + k0_, &Ws[BUF][(wid * 16 + 8) * 64]);      \
    }                                                                         \
  }

  const int ns = K / 64;

#define G_COMPUTE(CUR)                                                        \
  {                                                                           \
    _Pragma("unroll")                                                         \
    for (int kc = 0; kc < 2; ++kc) {                                          \
      short8 af[4], bf[NF];                                                   \
      _Pragma("unroll")                                                       \
      for (int mi = 0; mi < 4; ++mi) {                                        \
        const int row = wrow + mi * 16 + lr;                                  \
        af[mi] = *(const short8*)&As[CUR][row * 64 +                          \
                                          (((kc * 4 + lk) ^ (row & 7)) << 3)];\
      }                                                                       \
      _Pragma("unroll")                                                       \
      for (int ni = 0; ni < NF; ++ni) {                                       \
        const int row = wcol + ni * 16 + lr;                                  \
        bf[ni] = *(const short8*)&Ws[CUR][row * 64 +                          \
                                          (((kc * 4 + lk) ^ (row & 7)) << 3)];\
      }                                                                       \
      _Pragma("unroll")                                                       \
      for (int mi = 0; mi < 4; ++mi)                                          \
        _Pragma("unroll")                                                     \
        for (int ni = 0; ni < NF; ++ni)                                       \
          acc[mi][ni] = __builtin_amdgcn_mfma_f32_16x16x32_bf16(              \
              af[mi], bf[ni], acc[mi][ni], 0, 0, 0);                          \
    }                                                                         \
  }

  if constexpr (TN == 128) {
    // 2-buffer depth-1 pipeline
    G_STAGE(0, 0);
    asm volatile("s_waitcnt vmcnt(0)" ::: "memory");
    __builtin_amdgcn_s_barrier();
    for (int i = 0; i < ns; ++i) {
      const int cur = i & 1;
      if (i + 1 < ns) G_STAGE(i + 1, cur ^ 1);
      G_COMPUTE(cur);
      if (i + 1 < ns) {
        asm volatile("s_waitcnt vmcnt(0) lgkmcnt(0)" ::: "memory");
        __builtin_amdgcn_s_barrier();
      }
    }
  } else {
    // 3-buffer depth-2 pipeline (counted vmcnt, never 0 mid-loop)
    G_STAGE(0, 0);
    G_STAGE(1, 1);
    asm volatile("s_waitcnt vmcnt(6)" ::: "memory");
    __builtin_amdgcn_s_barrier();
    for (int i = 0; i < ns; ++i) {
      const int cur = i % 3;
      if (i + 2 < ns) G_STAGE(i + 2, (i + 2) % 3);
      G_COMPUTE(cur);
      if (i + 1 < ns) {
        if (i + 2 < ns)
          asm volatile("s_waitcnt vmcnt(6) lgkmcnt(0)" ::: "memory");
        else
          asm volatile("s_waitcnt vmcnt(0) lgkmcnt(0)" ::: "memory");
        __builtin_amdgcn_s_barrier();
      }
    }
  }
#undef G_STAGE
#undef G_COMPUTE

  if (VT && bcol >= vcol0) {
    const int vn_mask = (1 << vn_log2) - 1;
#pragma unroll
    for (int mi = 0; mi < 4; ++mi) {
#pragma unroll
      for (int ni = 0; ni < NF; ++ni) {
        int col = bcol + wcol + ni * 16 + lr;
        int vc = col - vcol0;
        int r0 = brow + wrow + mi * 16 + lk * 4;
        int bb = r0 >> vn_log2;
        int n = r0 & vn_mask;
        float bv = BIAS ? bias[col] : 0.f;
        short4v o;
#pragma unroll
        for (int j = 0; j < 4; ++j) o[j] = f2bf(acc[mi][ni][j] + bv);
        *(short4v*)(vt + (((size_t)(bb * 512 + vc)) << vn_log2) + n) = o;
      }
    }
    return;
  }

#pragma unroll
  for (int mi = 0; mi < 4; ++mi) {
#pragma unroll
    for (int ni = 0; ni < NF; ++ni) {
      int col = bcol + wcol + ni * 16 + lr;
      int row0 = brow + wrow + mi * 16 + lk * 4;
      float bv = BIAS ? bias[col] : 0.f;
#pragma unroll
      for (int j = 0; j < 4; ++j) {
        float v = acc[mi][ni][j] + bv;
        if (RELU) v = fmaxf(v, 0.f);
        if (col < oscale_end) v *= oscale;
        size_t oi = (size_t)(row0 + j) * NC + col;
        if (RESMODE == 1) v += ((const float*)res)[oi];
        if (RESMODE == 2) v += bf2f(((const short*)res)[oi]);
        if (OUTBF) ((short*)outp)[oi] = f2bf(v);
        else       ((float*)outp)[oi] = v;
      }
    }
  }
}

// ---------------- Flash attention v8 (32x32x16, in-register P, T12) ---------
// grid: 1D (Nq/128)*B*H, 256 thr = 4 waves; wave owns 32 q-rows.
// Swapped QK^T (A=K, B=Q); softmax = per-lane exp2 (scale pre-folded into Q);
// P -> PV B-fragments in-register: 8 cvt_pk + 4 permlane32_swap per 32-kv blk.
// K/V staged via glds + source-side XOR swizzle, double-buffered.
__global__ __launch_bounds__(256) void flash_attn8(
    const short* __restrict__ q, const short* __restrict__ k,
    const short* __restrict__ vt, short* __restrict__ out,
    int qstride, int kstride, int Nq, int Nkv, int vn_log2, int H_) {
  __shared__ short Ks[2 * 128 * 64];   // 32 KB
  __shared__ short Vs[2 * 64 * 128];   // 32 KB
  const int t = threadIdx.x;
  const int wid = t >> 6, lane = t & 63;
  const int l31 = lane & 31, lh = lane >> 5;
  const int nb = gridDim.x;
  const int b0 = blockIdx.x;
  const int bid = ((nb & 7) == 0) ? ((b0 & 7) * (nb >> 3) + (b0 >> 3)) : b0;
  const int gx = Nq >> 7;
  const int bh = bid / gx, qblk = bid - bh * gx;
  const int b = bh / H_, h = bh - b * H_;
  const int q0 = qblk * 128 + wid * 32;

  short8 qf[4];
  {
    const short* qp = q + ((size_t)b * Nq + q0 + l31) * qstride + h * 64 + lh * 8;
#pragma unroll
    for (int kc = 0; kc < 4; ++kc) qf[kc] = *(const short8*)(qp + kc * 16);
  }

  f32x16 o0 = {}, o1 = {};
  f32x16 lacc = {};

  const int krw = lane >> 3;
  const short* kG = k + ((size_t)b * Nkv + wid * 32 + krw) * kstride + h * 64 +
                    (((lane & 7) ^ krw) << 3);
  const short* vGp[4];
#pragma unroll
  for (int j = 0; j < 4; ++j)
    vGp[j] = vt + (((size_t)bh * 64 + wid * 16 + j * 4 + (lane >> 4)) << vn_log2) +
             (((lane & 15) ^ (j * 4 + (lane >> 4))) << 3);
  short* kD = &Ks[wid * 2048];
  short* vD = &Vs[wid * 2048];

#define STAGE_KV(KT, BUF)                                                     \
  {                                                                           \
    const short* kp_ = kG + (size_t)(KT) * kstride;                           \
    short* kd_ = kD + (BUF) * 8192;                                           \
    gl_lds16(kp_, kd_);                                                       \
    gl_lds16(kp_ + (size_t)8 * kstride, kd_ + 512);                           \
    gl_lds16(kp_ + (size_t)16 * kstride, kd_ + 1024);                         \
    gl_lds16(kp_ + (size_t)24 * kstride, kd_ + 1536);                         \
    short* vd_ = vD + (BUF) * 8192;                                           \
    gl_lds16(vGp[0] + (KT), vd_);                                             \
    gl_lds16(vGp[1] + (KT), vd_ + 512);                                       \
    gl_lds16(vGp[2] + (KT), vd_ + 1024);                                      \
    gl_lds16(vGp[3] + (KT), vd_ + 1536);                                      \
  }

  STAGE_KV(0, 0);
  __syncthreads();
  int cur = 0;

  for (int kt = 0; kt < Nkv; kt += 128) {
    if (kt + 128 < Nkv) STAGE_KV(kt + 128, cur ^ 1);

    const short* kbase = &Ks[cur * 8192];
    const short* vbase = &Vs[cur * 8192];

#pragma unroll
    for (int kk = 0; kk < 4; ++kk) {
      f32x16 s = {};
      {
        const int r = kk * 32 + l31;
        const short* krow = kbase + r * 64;
        const int rx = r & 7;
#pragma unroll
        for (int kc = 0; kc < 4; ++kc) {
          short8 kf = *(const short8*)(krow + (((kc * 2 + lh) ^ rx) << 3));
          s = __builtin_amdgcn_mfma_f32_32x32x16_bf16(kf, qf[kc], s, 0, 0, 0);
        }
      }
#pragma unroll
      for (int rr = 0; rr < 16; ++rr)
        s[rr] = __builtin_amdgcn_exp2f(s[rr]);
      lacc += s;
      unsigned w[8];
#pragma unroll
      for (int g = 0; g < 8; ++g)
        asm("v_cvt_pk_bf16_f32 %0, %1, %2" : "=v"(w[g]) : "v"(s[2 * g]), "v"(s[2 * g + 1]));
      pl32swap(w[0], w[2]); pl32swap(w[1], w[3]);
      pl32swap(w[4], w[6]); pl32swap(w[5], w[7]);
      union { unsigned u[4]; short8 s8; } pf0, pf1;
      pf0.u[0] = w[0]; pf0.u[1] = w[1]; pf0.u[2] = w[2]; pf0.u[3] = w[3];
      pf1.u[0] = w[4]; pf1.u[1] = w[5]; pf1.u[2] = w[6]; pf1.u[3] = w[7];
#pragma unroll
      for (int ch = 0; ch < 2; ++ch) {
        short8 pf = ch ? pf1.s8 : pf0.s8;
        const int c16 = kk * 4 + ch * 2 + lh;
        {
          const int d = l31;
          short8 vf = *(const short8*)(vbase + d * 128 + ((c16 ^ (d & 15)) << 3));
          o0 = __builtin_amdgcn_mfma_f32_32x32x16_bf16(vf, pf, o0, 0, 0, 0);
        }
        {
          const int d = 32 + l31;
          short8 vf = *(const short8*)(vbase + d * 128 + ((c16 ^ (d & 15)) << 3));
          o1 = __builtin_amdgcn_mfma_f32_32x32x16_bf16(vf, pf, o1, 0, 0, 0);
        }
      }
    }

    __syncthreads();
    cur ^= 1;
  }
#undef STAGE_KV

  float ls = (((lacc[0] + lacc[1]) + (lacc[2] + lacc[3])) +
              ((lacc[4] + lacc[5]) + (lacc[6] + lacc[7]))) +
             (((lacc[8] + lacc[9]) + (lacc[10] + lacc[11])) +
              ((lacc[12] + lacc[13]) + (lacc[14] + lacc[15])));
  ls += __shfl_xor(ls, 32);
  float inv = 1.f / ls;

  short* orow = out + ((size_t)b * Nq + q0 + l31) * 512 + h * 64 + 4 * lh;
#pragma unroll
  for (int g = 0; g < 4; ++g) {
    short4v w0, w1;
#pragma unroll
    for (int j = 0; j < 4; ++j) {
      w0[j] = f2bf(o0[4 * g + j] * inv);
      w1[j] = f2bf(o1[4 * g + j] * inv);
    }
    *(short4v*)(orow + 8 * g) = w0;
    *(short4v*)(orow + 32 + 8 * g) = w1;
  }
}

// ---------------------------------------------------------------------------
extern "C" void kernel_launch(void* const* d_in, const int* in_sizes, int n_in,
                              void* d_out, int out_size, void* d_ws, size_t ws_size,
                              hipStream_t stream) {
  (void)in_sizes; (void)n_in; (void)out_size; (void)ws_size;
  const float* cond  = (const float*)d_in[0];
  const float* x_in  = (const float*)d_in[1];
  const float* Wqkv  = (const float*)d_in[2];
  const float* b_qkv = (const float*)d_in[3];
  const float* Wo    = (const float*)d_in[4];
  const float* bo    = (const float*)d_in[5];
  const float* Wcq   = (const float*)d_in[6];
  const float* Wck   = (const float*)d_in[7];
  const float* Wcv   = (const float*)d_in[8];
  const float* Wco   = (const float*)d_in[9];
  const float* bco   = (const float*)d_in[10];
  const float* W1    = (const float*)d_in[11];
  const float* b1    = (const float*)d_in[12];
  const float* W2    = (const float*)d_in[13];
  const float* b2    = (const float*)d_in[14];
  float* out = (float*)d_out;

  const int Bv = 4, Nv = 2048, Mv = 512, Ev = 512, Hv = 8, MHv = 1024, CDv = 256;
  const int RN = Bv * Nv;   // 8192
  const int RM = Bv * Mv;   // 2048
  const float KSC = 0.125f * 1.44269504f;  // softmax scale * log2(e) -> folded into Q

  char* ws = (char*)d_ws;
  size_t off = 0;
  auto alloc = [&](size_t bytes) { void* p = ws + off; off += bytes; return p; };

  short* wqkv_b = (short*)alloc((size_t)3 * Ev * Ev * 2);
  short* wo_b   = (short*)alloc((size_t)Ev * Ev * 2);
  short* wcq_b  = (short*)alloc((size_t)Ev * Ev * 2);
  short* wck_b  = (short*)alloc((size_t)Ev * CDv * 2);   // adjacent to wcv_b!
  short* wcv_b  = (short*)alloc((size_t)Ev * CDv * 2);
  short* wco_b  = (short*)alloc((size_t)Ev * Ev * 2);
  short* w1_b   = (short*)alloc((size_t)MHv * Ev * 2);
  short* w2_b   = (short*)alloc((size_t)Ev * MHv * 2);
  short* cond_b = (short*)alloc((size_t)RM * CDv * 2);
  short* xnb    = (short*)alloc((size_t)RN * Ev * 2);          // xn/xn2/xn3
  short* sa_b   = (short*)alloc((size_t)RN * Ev * 2);
  short* x1     = (short*)alloc((size_t)RN * Ev * 2);          // bf16 residual
  short* x2     = (short*)alloc((size_t)RN * Ev * 2);          // bf16 residual
  char*  qreg   = (char*)alloc((size_t)RN * 3 * Ev * 2);       // 25.2MB region
  short* qkv_b  = (short*)qreg;
  // aliases (disjoint lifetimes):
  short* cq   = (short*)(qreg + 0);                                       // 8MB
  short* ck   = (short*)(qreg + (size_t)RN * Ev * 2);                     // 4MB (stride 1024)
  short* vt_c = (short*)(qreg + (size_t)RN * Ev * 2 + (size_t)4 * 1024 * 1024);
  short* ca   = (short*)(qreg + (size_t)RN * Ev * 2 + (size_t)6 * 1024 * 1024);
  short* hb   = (short*)(qreg + 0);          // MLP hidden, after cross-attn
  short* vt_s = (short*)x2;                  // self V^T (8.4MB), dead before x2 write

  // fused weight/cond casts
  CastArgs ca_args;
  const float* srcs[9] = {Wqkv, Wo, Wcq, Wck, Wcv, Wco, W1, W2, cond};
  short* dsts[9] = {wqkv_b, wo_b, wcq_b, wck_b, wcv_b, wco_b, w1_b, w2_b, cond_b};
  int ns_[9] = {3*Ev*Ev, Ev*Ev, Ev*Ev, Ev*CDv, Ev*CDv, Ev*Ev, MHv*Ev, Ev*MHv, RM*CDv};
  int tot_blk = 0;
  for (int i = 0; i < 9; ++i) {
    ca_args.d[i].src = srcs[i]; ca_args.d[i].dst = dsts[i];
    ca_args.d[i].nblk = ns_[i] / 2048; tot_blk += ca_args.d[i].nblk;
  }
  cast_multi<<<tot_blk, 256, 0, stream>>>(ca_args);

  dim3 blk(256);

  // 1) LN(x_in fp32) -> xnb
  ln_kernel<false><<<RN / 4, blk, 0, stream>>>(x_in, xnb, RN);
  // 2) qkv (TN=128): q (cols<512, pre-scaled KSC), k -> qkv_b; v -> vt_s^T
  gemm_nt<128, 0, true, false, true, true><<<(3 * Ev / 128) * (RN / 128), blk, 0, stream>>>(
      xnb, wqkv_b, b_qkv, nullptr, qkv_b, RN, 3 * Ev, Ev, 3 * Ev / 128,
      vt_s, 2 * Ev, 11, KSC, Ev);
  // 3) self-attn
  flash_attn8<<<(Nv / 128) * Bv * Hv, blk, 0, stream>>>(
      qkv_b, qkv_b + Ev, vt_s, sa_b, 3 * Ev, 3 * Ev, Nv, Nv, 11, Hv);
  // 4) x1 = sa @ Wo^T + bo + x_in  (bf16 out, fp32 res)
  gemm_nt<64, 1, true, false, true, false><<<(Ev / 64) * (RN / 128), blk, 0, stream>>>(
      sa_b, wo_b, bo, x_in, x1, RN, Ev, Ev, Ev / 64, nullptr, 0, 0, 1.f, 0);
  // 5) LN(x1 bf16) -> xnb
  ln_kernel<true><<<RN / 4, blk, 0, stream>>>(x1, xnb, RN);
  // 6) cq = (xnb @ Wcq^T) * KSC
  gemm_nt<64, 0, false, false, true, false><<<(Ev / 64) * (RN / 128), blk, 0, stream>>>(
      xnb, wcq_b, nullptr, nullptr, cq, RN, Ev, Ev, Ev / 64, nullptr, 0, 0, KSC, Ev);
  // 7) [ck | cv] = cond @ [Wck;Wcv]^T one GEMM; cv half -> vt_c transposed
  gemm_nt<64, 0, false, false, true, true><<<(2 * Ev / 64) * (RM / 128), blk, 0, stream>>>(
      cond_b, wck_b, nullptr, nullptr, ck, RM, 2 * Ev, CDv, 2 * Ev / 64,
      vt_c, Ev, 9, 1.f, 0);
  // 8) cross-attn (k rows stride 1024)
  flash_attn8<<<(Nv / 128) * Bv * Hv, blk, 0, stream>>>(
      cq, ck, vt_c, ca, Ev, 2 * Ev, Nv, Mv, 9, Hv);
  // 9) x2 = ca @ Wco^T + bco + x1 (bf16 out, bf16 res)
  gemm_nt<64, 2, true, false, true, false><<<(Ev / 64) * (RN / 128), blk, 0, stream>>>(
      ca, wco_b, bco, x1, x2, RN, Ev, Ev, Ev / 64, nullptr, 0, 0, 1.f, 0);
  // 10) LN(x2 bf16) -> xnb
  ln_kernel<true><<<RN / 4, blk, 0, stream>>>(x2, xnb, RN);
  // 11) h = relu(xnb @ W1^T + b1)  (TN=128)
  gemm_nt<128, 0, true, true, true, false><<<(MHv / 128) * (RN / 128), blk, 0, stream>>>(
      xnb, w1_b, b1, nullptr, hb, RN, MHv, Ev, MHv / 128, nullptr, 0, 0, 1.f, 0);
  // 12) out = relu(h @ W2^T + b2) + x2 (fp32 out, bf16 res)
  gemm_nt<64, 2, true, true, false, false><<<(Ev / 64) * (RN / 128), blk, 0, stream>>>(
      hb, w2_b, b2, x2, out, RN, Ev, MHv, Ev / 64, nullptr, 0, 0, 1.f, 0);
}